// Round 5
// baseline (448.279 us; speedup 1.0000x reference)
//
#include <hip/hip_runtime.h>
#include <cstdint>
#include <cstddef>

typedef __bf16 bf16;
typedef __bf16 bf16x8 __attribute__((ext_vector_type(8)));
typedef float f32x4 __attribute__((ext_vector_type(4)));

#define BDIM 4
#define TDIM 2048
#define DDIM 2048
#define HDIM 8
#define DHD 256
#define MTOT 8192
#define NCHUNK 64
#define LCHUNK 32

// async 16B global->LDS; LDS dest = wave-uniform base + lane*16
__device__ __forceinline__ void stage16(const bf16* g, bf16* l) {
  __builtin_amdgcn_global_load_lds(
      (const __attribute__((address_space(1))) void*)g,
      (__attribute__((address_space(3))) void*)l, 16, 0, 0);
}

// raw barrier / counted waits with compiler memory fences (no auto vmcnt(0) drain)
#define SBAR() asm volatile("s_barrier" ::: "memory")
#define WAITVM(N) asm volatile("s_waitcnt vmcnt(" #N ")" ::: "memory")

__device__ __forceinline__ float sigmoid_f(float x) {
  return __fdividef(1.f, 1.f + __expf(-x));
}
__device__ __forceinline__ float gelu_tanh(float v) {
  float u = 0.7978845608028654f * (v + 0.044715f * v * v * v);
  u = fminf(fmaxf(u, -15.f), 15.f);
  float t = __expf(2.f * u);                       // tanh(u) = (t-1)/(t+1)
  return 0.5f * v * (1.f + __fdividef(t - 1.f, t + 1.f));
}
__device__ __forceinline__ float softplus_f(float x) {
  return __logf(1.f + __expf(x));                  // x in [-1.2, 0.4] here
}

// ---------------------------------------------------------------------------
// fp32 -> bf16 bulk convert, 8 elem/thread (count must be /2048)
// ---------------------------------------------------------------------------
__global__ __launch_bounds__(256) void f2b(const float* __restrict__ src,
                                           bf16* __restrict__ dst) {
  size_t i = ((size_t)blockIdx.x * 256 + threadIdx.x) * 8;
  const float4 a = *(const float4*)(src + i);
  const float4 b = *(const float4*)(src + i + 4);
  bf16x8 r;
  r[0] = (bf16)a.x; r[1] = (bf16)a.y; r[2] = (bf16)a.z; r[3] = (bf16)a.w;
  r[4] = (bf16)b.x; r[5] = (bf16)b.y; r[6] = (bf16)b.z; r[7] = (bf16)b.w;
  *(bf16x8*)(dst + i) = r;
}

// ---------------------------------------------------------------------------
// C[m,n] = epi(sum_k A[m,k]*B[n,k] + bias[n]); bf16 operands, fp32 accum.
// 256x256 tile, BK=64, 8 waves (2M x 4N), LDS [buf][khalf][256][32] x {A,B}.
// 4 phases per K-tile = (ks,nh) in (0,0),(0,1),(1,0),(1,1); 16 MFMA each.
// ONE barrier per phase: {ds_read; stage 1 half-tile; MFMA; [vmcnt(10)]; SBAR}
//  - reads of phase k are certified by the vmcnt(10)+SBAR at end of ph(k-2|k-1)
//    gate (data staged >=6 phases earlier); waves start MFMA on own lgkm ->
//    cross-wave LDS/MFMA overlap (no pre-MFMA barrier).
//  - stage targets: ph1: BK1(t+1)->buf p^1; ph2: AK0(t+2)->buf p;
//    ph3: BK0(t+2); ph4: AK1(t+2). Each slot died in the previous phase
//    (last read there; end-of-phase barrier makes that global).
//  - vmcnt(10) at ph2/ph4 end = 5 half-tiles in flight, never drains in-loop.
//    Ledger (wave-local, 2 loads/half-tile, 1 stage/phase):
//      ph2-gate certifies ...BK1(t) -> ph3/ph4 reads valid
//      ph4-gate certifies ...BK0(t+1) -> next ph1/ph2 reads valid
//  - tail: stage sources clamped to tile NT-1 (garbage into dead slots) so
//    the vmcnt ledger stays uniform; WAITVM(0) after loop drains.
// Swizzle: 32k-row = 4x16B slots; slot' = slot ^ (r&3) ^ ((r>>2)&3).
//   write side: linear LDS dest + pre-swizzled global k-chunk (rule 21);
//   read side: slot = quad ^ (l15&3) ^ ((l15>>2)&3)  -> bank-balanced b128.
// XCD-chunked block swizzle. Requires M,N%256==0, K%64==0, K/64>=2, nwg%8==0.
// ---------------------------------------------------------------------------
template <typename TO, int EPI>
__global__ __launch_bounds__(512, 2) void gemm256(
    const bf16* __restrict__ A, const bf16* __restrict__ Bm,
    const float* __restrict__ bias, TO* __restrict__ C,
    int K, int lda, int ldb, int ldc) {
  const int gx = gridDim.x, gy = gridDim.y;
  const int nwg = gx * gy;
  const int did = blockIdx.x + gx * blockIdx.y;
  const int cpx = nwg >> 3;                       // chunk per XCD
  const int lid = (did & 7) * cpx + (did >> 3);
  const int n0 = (lid % gx) * 256;
  const int m0 = (lid / gx) * 256;

  __shared__ bf16 sA[2][2][256][32];   // 64 KiB
  __shared__ bf16 sB[2][2][256][32];   // 64 KiB
  const int tid = threadIdx.x;
  const int lane = tid & 63;
  const int wid = tid >> 6;         // 0..7
  const int wr = wid >> 2;          // M-half (128 rows)
  const int wc = wid & 3;           // N-quarter (64 cols)
  const int quad = lane >> 4;
  const int l15 = lane & 15;

  // read-side swizzled slot (element offset within 32-el row)
  const int slot = (quad ^ (l15 & 3) ^ ((l15 >> 2) & 3)) * 8;
  const int aoff = (wr * 128 + l15) * 32 + slot;
  const int boff = (wc * 64 + l15) * 32 + slot;

  // stage-side: lane covers row rg (+j*16), k-chunk pre-swizzled (j-invariant)
  const int rg = wid * 32 + (lane >> 2);
  const int kx = ((lane & 3) ^ (rg & 3) ^ ((rg >> 2) & 3)) * 8;
  const bf16* AgS = A + (size_t)(m0 + rg) * lda + kx;
  const bf16* BgS = Bm + (size_t)(n0 + rg) * ldb + kx;

  f32x4 acc[8][4];
#pragma unroll
  for (int i = 0; i < 8; ++i)
#pragma unroll
    for (int j = 0; j < 4; ++j)
#pragma unroll
      for (int r = 0; r < 4; ++r) acc[i][j][r] = 0.f;

  const int NT = K >> 6;

  // stage one K-half half-tile (16 KB): 2 x stage16 per wave
#define STA(P, KS, TK)                                                        \
  do {                                                                        \
    _Pragma("unroll") for (int j_ = 0; j_ < 2; ++j_)                          \
        stage16(AgS + (size_t)j_ * 16 * lda + (TK) * 64 + (KS) * 32,          \
                &sA[P][KS][wid * 32 + j_ * 16][0]);                           \
  } while (0)
#define STB(P, KS, TK)                                                        \
  do {                                                                        \
    _Pragma("unroll") for (int j_ = 0; j_ < 2; ++j_)                          \
        stage16(BgS + (size_t)j_ * 16 * ldb + (TK) * 64 + (KS) * 32,          \
                &sB[P][KS][wid * 32 + j_ * 16][0]);                           \
  } while (0)

  bf16x8 af[8], bfr[2];

#define RD_A(KS)                                                              \
  do {                                                                        \
    _Pragma("unroll") for (int mi_ = 0; mi_ < 8; ++mi_)                       \
        af[mi_] = *(const bf16x8*)(Ab + (KS) * 8192 + mi_ * 512);             \
  } while (0)
#define RD_B(KS, NH)                                                          \
  do {                                                                        \
    _Pragma("unroll") for (int ni_ = 0; ni_ < 2; ++ni_)                       \
        bfr[ni_] = *(const bf16x8*)(Bb + (KS) * 8192 + (NH) * 1024 + ni_ * 512); \
  } while (0)
#define MFMA16(NH)                                                            \
  do {                                                                        \
    __builtin_amdgcn_s_setprio(1);                                            \
    _Pragma("unroll") for (int mi_ = 0; mi_ < 8; ++mi_)                       \
        _Pragma("unroll") for (int ni_ = 0; ni_ < 2; ++ni_)                   \
            acc[mi_][(NH)*2 + ni_] = __builtin_amdgcn_mfma_f32_16x16x32_bf16( \
                af[mi_], bfr[ni_], acc[mi_][(NH)*2 + ni_], 0, 0, 0);          \
    __builtin_amdgcn_s_setprio(0);                                            \
  } while (0)

  // prologue: tile0 all 4 halves + tile1 {AK0,BK0,AK1}; BK1(1) staged at ph1.
  STA(0, 0, 0); STB(0, 0, 0); STA(0, 1, 0); STB(0, 1, 0);
  STA(1, 0, 1); STB(1, 0, 1); STA(1, 1, 1);
  WAITVM(10);   // 14 outstanding -> retire tile0's 4 halves
  SBAR();

  for (int t = 0; t < NT; ++t) {
    const int p = t & 1;
    const bf16* Ab = &sA[p][0][0][0] + aoff;
    const bf16* Bb = &sB[p][0][0][0] + boff;
    const int tk1 = (t + 1 < NT) ? t + 1 : NT - 1;
    const int tk2 = (t + 2 < NT) ? t + 2 : NT - 1;
    // ph1 (ks0, nh0)
    RD_A(0); RD_B(0, 0);
    STB(p ^ 1, 1, tk1);            // BK1(t+1); slot died (t-1,ph4)
    MFMA16(0);
    SBAR();
    // ph2 (ks0, nh1)
    RD_B(0, 1);
    STA(p, 0, tk2);                // AK0(t+2); slot died ph1
    MFMA16(1);
    WAITVM(10);                    // certifies AK1(t), BK1(t) for ph3/ph4
    SBAR();
    // ph3 (ks1, nh0)
    RD_A(1); RD_B(1, 0);
    STB(p, 0, tk2);                // BK0(t+2); slot died ph2
    MFMA16(0);
    SBAR();
    // ph4 (ks1, nh1)
    RD_B(1, 1);
    STA(p, 1, tk2);                // AK1(t+2); slot died ph3
    MFMA16(1);
    WAITVM(10);                    // certifies AK0(t+1), BK0(t+1) for next ph1/2
    SBAR();
  }
  WAITVM(0);                       // drain tail garbage stages

#undef STA
#undef STB
#undef RD_A
#undef RD_B
#undef MFMA16

#pragma unroll
  for (int nn = 0; nn < 4; ++nn) {
    const int n = n0 + wc * 64 + nn * 16 + l15;
    const float bv = bias[n];
#pragma unroll
    for (int mm = 0; mm < 8; ++mm) {
#pragma unroll
      for (int r = 0; r < 4; ++r) {
        const int m = m0 + wr * 128 + mm * 16 + quad * 4 + r;
        float v = acc[mm][nn][r] + bv;
        if (EPI == 1) v = gelu_tanh(v);
        C[(size_t)m * ldc + n] = (TO)v;
      }
    }
  }
}

// ---------------------------------------------------------------------------
// gate pre-activation GEMM: one gate per block (z = h*2+g), 128x128 tile,
// K = DH = 256. out[m, h*DHD + n] = sum_k xconv[m, h*DHD+k] * W[g][h][n][k]
// ---------------------------------------------------------------------------
__global__ __launch_bounds__(256) void gate_gemm(
    const bf16* __restrict__ xconv,
    const bf16* __restrict__ gxT, const bf16* __restrict__ gaT,
    bf16* __restrict__ gxr, bf16* __restrict__ gar) {
  const int h = blockIdx.z >> 1;
  const int g = blockIdx.z & 1;
  const bf16* A = xconv + h * DHD;                       // lda = DDIM
  const bf16* Bm = (g ? gaT : gxT) + (size_t)h * DHD * DHD;  // ldb = DHD
  bf16* C = (g ? gar : gxr) + h * DHD;                   // ldc = DDIM
  const int n0 = blockIdx.x * 128;
  const int m0 = blockIdx.y * 128;
  __shared__ bf16 As[128 * 32];
  __shared__ bf16 Bs[128 * 32];
  const int tid = threadIdx.x;
  const int lane = tid & 63;
  const int wid = tid >> 6;
  const int waveM = wid >> 1, waveN = wid & 1;
  const int quad = lane >> 4;
  const int l15 = lane & 15;
  const int srow = lane >> 2;
  const int scol = (lane & 3) * 8;

  f32x4 acc[4][4];
#pragma unroll
  for (int i = 0; i < 4; ++i)
#pragma unroll
    for (int j = 0; j < 4; ++j)
#pragma unroll
      for (int r = 0; r < 4; ++r) acc[i][j][r] = 0.f;

  for (int k0 = 0; k0 < DHD; k0 += 32) {
    if (k0) __syncthreads();
#pragma unroll
    for (int cc = 0; cc < 2; ++cc) {
      const int q = wid * 2 + cc;
      const int row = q * 16 + srow;
      stage16(A + (size_t)(m0 + row) * DDIM + k0 + scol, As + q * 512);
      stage16(Bm + (size_t)(n0 + row) * DHD + k0 + scol, Bs + q * 512);
    }
    __syncthreads();
    bf16x8 af[4], bfr[4];
#pragma unroll
    for (int i = 0; i < 4; ++i) {
      af[i]  = *(const bf16x8*)&As[(waveM * 64 + i * 16 + l15) * 32 + quad * 8];
      bfr[i] = *(const bf16x8*)&Bs[(waveN * 64 + i * 16 + l15) * 32 + quad * 8];
    }
#pragma unroll
    for (int i = 0; i < 4; ++i)
#pragma unroll
      for (int j = 0; j < 4; ++j)
        acc[i][j] = __builtin_amdgcn_mfma_f32_16x16x32_bf16(af[i], bfr[j], acc[i][j], 0, 0, 0);
  }

#pragma unroll
  for (int j = 0; j < 4; ++j) {
    const int n = n0 + waveN * 64 + j * 16 + l15;
#pragma unroll
    for (int i = 0; i < 4; ++i) {
#pragma unroll
      for (int r = 0; r < 4; ++r) {
        const int m = m0 + waveM * 64 + i * 16 + quad * 4 + r;
        C[(size_t)m * DDIM + n] = (bf16)acc[i][j][r];
      }
    }
  }
}

// ---------------------------------------------------------------------------
// depthwise causal conv, TW=4; bf16 data, fp32 weights
// ---------------------------------------------------------------------------
__global__ __launch_bounds__(256) void conv_kernel(
    const bf16* __restrict__ xp, const float* __restrict__ cw,
    const float* __restrict__ cb, const int* __restrict__ segp,
    bf16* __restrict__ xc) {
  int v = blockIdx.x * 256 + threadIdx.x;
  int dv = v & (DDIM / 8 - 1);
  int m = v >> 8;
  int d0 = dv * 8;
  int t = m & (TDIM - 1);
  int sp = segp[m];
  float acc[8];
#pragma unroll
  for (int j = 0; j < 8; ++j) acc[j] = cb[d0 + j];
#pragma unroll
  for (int i = 0; i < 4; ++i) {
    int shift = 3 - i;
    if (t >= shift && sp >= shift) {
      bf16x8 xv = *(const bf16x8*)&xp[(size_t)(m - shift) * DDIM + d0];
#pragma unroll
      for (int j = 0; j < 8; ++j) acc[j] = fmaf((float)xv[j], cw[i * DDIM + d0 + j], acc[j]);
    }
  }
  bf16x8 o;
#pragma unroll
  for (int j = 0; j < 8; ++j) o[j] = (bf16)acc[j];
  *(bf16x8*)&xc[(size_t)m * DDIM + d0] = o;
}

// ---------------------------------------------------------------------------
// transpose + convert gate weights: dst[h][j][i] = (bf16)src[h][i][j]
// ---------------------------------------------------------------------------
__global__ __launch_bounds__(256) void transpose_gates(
    const float* __restrict__ gxw, const float* __restrict__ gaw,
    bf16* __restrict__ gxT, bf16* __restrict__ gaT) {
  __shared__ bf16 tile[32][33];
  int zz = blockIdx.z;
  int h = zz >> 1;
  const float* src = (zz & 1) ? gaw : gxw;
  bf16* dst = (zz & 1) ? gaT : gxT;
  int j0 = blockIdx.x * 32;
  int i0 = blockIdx.y * 32;
  int r = threadIdx.x >> 5;
  int c = threadIdx.x & 31;
  for (int rr = r; rr < 32; rr += 8)
    tile[rr][c] = (bf16)src[(size_t)(h * DHD + i0 + rr) * DHD + j0 + c];
  __syncthreads();
  for (int rr = r; rr < 32; rr += 8)
    dst[(size_t)(h * DHD + j0 + rr) * DHD + i0 + c] = tile[c][rr];
}

// ---------------------------------------------------------------------------
// RG-LRU elementwise recompute, shared by scan phases
// ---------------------------------------------------------------------------
__device__ __forceinline__ void lru_elem(float pgx, float pga, float xc,
                                         float spv, bool reset,
                                         float& a, float& nr) {
  const float gx = sigmoid_f(pgx);
  const float ga = sigmoid_f(pga);
  const float la = -8.f * ga * spv;
  a = reset ? 0.f : __expf(la);
  const float mult = reset ? 1.f : sqrtf(fmaxf(1.f - __expf(2.f * la), 0.f));
  nr = xc * gx * mult;
}

// chunked scan phase 1: per (b, chunk, d) compute prod(a) and h across chunk
__global__ __launch_bounds__(256) void scan_phase1(
    const bf16* __restrict__ gxr, const bf16* __restrict__ gar,
    const bf16* __restrict__ xconv,
    const float* __restrict__ gxb, const float* __restrict__ gab,
    const float* __restrict__ apar, const int* __restrict__ segp,
    float* __restrict__ chA, float* __restrict__ chH) {
  int idx = blockIdx.x * 256 + threadIdx.x;
  int d = idx & (DDIM - 1);
  int c = (idx >> 11) & (NCHUNK - 1);
  int b = idx >> 17;
  const float gxbv = gxb[d], gabv = gab[d];
  const float spv = softplus_f(apar[d]);
  const int mrow = b * TDIM + c * LCHUNK;
  size_t base = (size_t)mrow * DDIM + d;
  float A = 1.f, hh = 0.f;
  for (int i = 0; i < LCHUNK; ++i) {
    size_t o = base + (size_t)i * DDIM;
    float a, nr;
    lru_elem((float)gxr[o] + gxbv, (float)gar[o] + gabv, (float)xconv[o],
             spv, segp[mrow + i] == 0, a, nr);
    hh = fmaf(a, hh, nr);
    A *= a;
  }
  int ci = (b * NCHUNK + c) * DDIM + d;
  chA[ci] = A;
  chH[ci] = hh;
}

__global__ __launch_bounds__(256) void scan_phase2(
    const float* __restrict__ chA, const float* __restrict__ chH,
    float* __restrict__ hst) {
  int idx = blockIdx.x * 256 + threadIdx.x;
  int d = idx & (DDIM - 1);
  int b = idx >> 11;
  float s = 0.f;
  for (int c = 0; c < NCHUNK; ++c) {
    int ci = (b * NCHUNK + c) * DDIM + d;
    hst[ci] = s;
    s = fmaf(chA[ci], s, chH[ci]);
  }
}

// phase 3: replay scan with chunk-start state; z = h*y in-place over y
__global__ __launch_bounds__(256) void scan_phase3(
    const bf16* __restrict__ gxr, const bf16* __restrict__ gar,
    const bf16* __restrict__ xconv,
    const float* __restrict__ gxb, const float* __restrict__ gab,
    const float* __restrict__ apar, const int* __restrict__ segp,
    const float* __restrict__ hst, bf16* __restrict__ yz) {
  int idx = blockIdx.x * 256 + threadIdx.x;
  int d = idx & (DDIM - 1);
  int c = (idx >> 11) & (NCHUNK - 1);
  int b = idx >> 17;
  const float gxbv = gxb[d], gabv = gab[d];
  const float spv = softplus_f(apar[d]);
  const int mrow = b * TDIM + c * LCHUNK;
  size_t base = (size_t)mrow * DDIM + d;
  float hh = hst[(b * NCHUNK + c) * DDIM + d];
  for (int i = 0; i < LCHUNK; ++i) {
    size_t o = base + (size_t)i * DDIM;
    float a, nr;
    lru_elem((float)gxr[o] + gxbv, (float)gar[o] + gabv, (float)xconv[o],
             spv, segp[mrow + i] == 0, a, nr);
    hh = fmaf(a, hh, nr);
    yz[o] = (bf16)(hh * (float)yz[o]);
  }
}

// ---------------------------------------------------------------------------
extern "C" void kernel_launch(void* const* d_in, const int* in_sizes, int n_in,
                              void* d_out, int out_size, void* d_ws, size_t ws_size,
                              hipStream_t stream) {
  const float* x    = (const float*)d_in[0];
  const int*   segp = (const int*)d_in[1];
  const float* Wy   = (const float*)d_in[2];
  const float* by   = (const float*)d_in[3];
  const float* Wx   = (const float*)d_in[4];
  const float* bx   = (const float*)d_in[5];
  const float* cw   = (const float*)d_in[6];
  const float* cb   = (const float*)d_in[7];
  const float* gxw  = (const float*)d_in[8];
  const float* gxb  = (const float*)d_in[9];
  const float* gaw  = (const float*)d_in[10];
  const float* gab  = (const float*)d_in[11];
  const float* apar = (const float*)d_in[12];
  const float* Wout = (const float*)d_in[13];
  const float* bout = (const float*)d_in[14];

  const size_t MD = (size_t)MTOT * DDIM;       // 16.78M elements
  const size_t WD = (size_t)DDIM * DDIM;       // 4.19M elements
  // d_out (fp32, 67 MB) as bf16 scratch until the final GEMM:
  bf16* xb    = (bf16*)d_out;                   // lower: xb -> xconv
  bf16* xproj = (bf16*)((char*)d_out + MD * 2); // upper: xproj -> gxr
  bf16* xconv = xb;
  bf16* gxr   = xproj;

  // ws (~92 MB): gar | W1 | WB1 | WB2 | gxT | gaT | chA | chH | hst
  char* ws = (char*)d_ws;
  bf16*  gar = (bf16*)ws;                        // 33.5 MB
  bf16*  W1  = (bf16*)(ws + MD * 2);             // y -> z (33.5 MB)
  bf16*  WB1 = (bf16*)(ws + 2 * MD * 2);         // Wxb, later Woutb (8.4 MB)
  bf16*  WB2 = (bf16*)(ws + 2 * MD * 2 + WD * 2);// Wyb (8.4 MB)
  char*  tail = ws + 2 * MD * 2 + 2 * WD * 2;
  const size_t GW = (size_t)HDIM * DHD * DHD * 2;      // 1 MiB
  const size_t CH = (size_t)BDIM * NCHUNK * DDIM * 4;  // 2 MiB
  bf16*  gxT = (bf16*)tail;
  bf16*  gaT = (bf16*)(tail + GW);
  float* chA = (float*)(tail + 2 * GW);
  float* chH = (float*)(tail + 2 * GW + CH);
  float* hst = (float*)(tail + 2 * GW + 2 * CH);

  dim3 blk(256);
  f2b<<<dim3(MD / 2048), blk, 0, stream>>>(x, xb);
  f2b<<<dim3(WD / 2048), blk, 0, stream>>>(Wx, WB1);
  f2b<<<dim3(WD / 2048), blk, 0, stream>>>(Wy, WB2);
  transpose_gates<<<dim3(8, 8, 16), blk, 0, stream>>>(gxw, gaw, gxT, gaT);

  // xproj = x @ Wx^T + bx ; y = gelu(x @ Wy^T + by)   (256^2, 1-bar/phase pipe)
  gemm256<bf16, 0><<<dim3(8, 32), dim3(512), 0, stream>>>(xb, WB1, bx, xproj, DDIM, DDIM, DDIM, DDIM);
  gemm256<bf16, 1><<<dim3(8, 32), dim3(512), 0, stream>>>(xb, WB2, by, W1, DDIM, DDIM, DDIM, DDIM);

  // xconv in-place over xb (reads xproj; xb dead after the two GEMMs)
  conv_kernel<<<dim3(MTOT * (DDIM / 8) / 256), blk, 0, stream>>>(xproj, cw, cb, segp, xconv);

  // gate pre-activations: gxr over xproj (dead), gar in ws
  gate_gemm<<<dim3(2, 64, 16), blk, 0, stream>>>(xconv, gxT, gaT, gxr, gar);

  // chunked scan with fused RG-LRU elementwise; phase3 writes z = h*y over y
  scan_phase1<<<dim3(BDIM * NCHUNK * DDIM / 256), blk, 0, stream>>>(
      gxr, gar, xconv, gxb, gab, apar, segp, chA, chH);
  scan_phase2<<<dim3(BDIM * DDIM / 256), blk, 0, stream>>>(chA, chH, hst);
  scan_phase3<<<dim3(BDIM * NCHUNK * DDIM / 256), blk, 0, stream>>>(
      gxr, gar, xconv, gxb, gab, apar, segp, hst, W1);

  // out = z @ Wout^T + bout (fp32 over all of d_out; scratch dead)
  f2b<<<dim3(WD / 2048), blk, 0, stream>>>(Wout, WB1);
  gemm256<float, 0><<<dim3(8, 32), dim3(512), 0, stream>>>(W1, WB1, bout, (float*)d_out, DDIM, DDIM, DDIM, DDIM);
}

// Round 6
// 407.274 us; speedup vs baseline: 1.1007x; 1.1007x over previous
//
#include <hip/hip_runtime.h>
#include <cstdint>
#include <cstddef>

typedef __bf16 bf16;
typedef __bf16 bf16x8 __attribute__((ext_vector_type(8)));
typedef float f32x4 __attribute__((ext_vector_type(4)));

#define BDIM 4
#define TDIM 2048
#define DDIM 2048
#define HDIM 8
#define DHD 256
#define MTOT 8192
#define NCHUNK 64
#define LCHUNK 32

// async 16B global->LDS; LDS dest = wave-uniform base + lane*16
__device__ __forceinline__ void stage16(const bf16* g, bf16* l) {
  __builtin_amdgcn_global_load_lds(
      (const __attribute__((address_space(1))) void*)g,
      (__attribute__((address_space(3))) void*)l, 16, 0, 0);
}

// CRITICAL: intrinsic barrier (no implicit vmcnt/lgkm drain) and BARE asm
// waitcnt (no "memory" clobber). A "memory"-clobbered asm is treated as an
// unknown memory access -> the backend inserts s_waitcnt vmcnt(0) lgkmcnt(0)
// before it, silently serializing the whole pipeline (rounds 1-5 bug).
#define BARX() __builtin_amdgcn_s_barrier()
#define SCHB() __builtin_amdgcn_sched_barrier(0)
#define WAITVM(N) asm volatile("s_waitcnt vmcnt(" #N ")")

__device__ __forceinline__ float sigmoid_f(float x) {
  return __fdividef(1.f, 1.f + __expf(-x));
}
__device__ __forceinline__ float gelu_tanh(float v) {
  float u = 0.7978845608028654f * (v + 0.044715f * v * v * v);
  u = fminf(fmaxf(u, -15.f), 15.f);
  float t = __expf(2.f * u);                       // tanh(u) = (t-1)/(t+1)
  return 0.5f * v * (1.f + __fdividef(t - 1.f, t + 1.f));
}
__device__ __forceinline__ float softplus_f(float x) {
  return __logf(1.f + __expf(x));                  // x in [-1.2, 0.4] here
}

// ---------------------------------------------------------------------------
// fp32 -> bf16 bulk convert, 8 elem/thread (count must be /2048)
// ---------------------------------------------------------------------------
__global__ __launch_bounds__(256) void f2b(const float* __restrict__ src,
                                           bf16* __restrict__ dst) {
  size_t i = ((size_t)blockIdx.x * 256 + threadIdx.x) * 8;
  const float4 a = *(const float4*)(src + i);
  const float4 b = *(const float4*)(src + i + 4);
  bf16x8 r;
  r[0] = (bf16)a.x; r[1] = (bf16)a.y; r[2] = (bf16)a.z; r[3] = (bf16)a.w;
  r[4] = (bf16)b.x; r[5] = (bf16)b.y; r[6] = (bf16)b.z; r[7] = (bf16)b.w;
  *(bf16x8*)(dst + i) = r;
}

// ---------------------------------------------------------------------------
// C[m,n] = epi(sum_k A[m,k]*B[n,k] + bias[n]); bf16 operands, fp32 accum.
// 256x256 tile, BK=64, 8 waves (2M x 4N), LDS [2][256][64] x {A,B} (128 KiB),
// XOR-8 16B-slot swizzle (0 conflicts measured, rounds 1-4).
//
// m201-style 4-phase pipeline, reads issued ONE PHASE AHEAD of consumption:
//   ph1: rd b1(t)[4]        ; stage HB1(t+1)->~p ; MFMA(0,0) aq0xb0 ; BAR
//   ph2: rd aq1=sub1(t)[8]  ; stage HA1(t+1)->~p ; MFMA(0,1) aq0xb1 ; BAR
//   ph3: (no reads)         ; stage HB0(t+2)->p  ; MFMA(1,0) aq1xb0 ; BAR
//   ph4: rd aq0=sub0(t+1),b0=nh0(t+1) [12, from ~p]
//                           ; stage HA0(t+2)->p  ; MFMA(1,1) aq1xb1 ; BAR
// Each phase's reads service UNDER its (register-fed) MFMA; compiler inserts
// fine-grained lgkm waits before the consuming MFMA one phase later.
// Stage safety (stage at ph k needs region's reads issued <= ph k-2, certified
// by BAR(k-1)): HB1->B[~p]hi last read ph1(t-1) ok; HA1->A[~p]hi last ph2(t-1)
// ok; HB0->B[p]lo last ph1(t) ok; HA0->A[p]lo last ph2(t) ok.
// Counted gates (2 loads per stage, never drain in-loop):
//   ph1 start: vmcnt(4) retires HB1(t),HA1(t)   (for ph1/ph2 reads)
//   ph4 start: vmcnt(6) retires HA0(t+1),HB0(t+1) (for ph4 reads)
// XCD-chunked block swizzle. Requires M,N%256==0, K%64==0, K/64>=2, nwg%8==0.
// ---------------------------------------------------------------------------
template <typename TO, int EPI>
__global__ __launch_bounds__(512, 2) void gemm256(
    const bf16* __restrict__ A, const bf16* __restrict__ Bm,
    const float* __restrict__ bias, TO* __restrict__ C,
    int K, int lda, int ldb, int ldc) {
  const int gx = gridDim.x, gy = gridDim.y;
  const int nwg = gx * gy;
  const int did = blockIdx.x + gx * blockIdx.y;
  const int cpx = nwg >> 3;                       // chunk per XCD
  const int lid = (did & 7) * cpx + (did >> 3);
  const int n0 = (lid % gx) * 256;
  const int m0 = (lid / gx) * 256;

  __shared__ bf16 sA[2][256][64];   // 64 KiB
  __shared__ bf16 sB[2][256][64];   // 64 KiB
  const int tid = threadIdx.x;
  const int lane = tid & 63;
  const int wid = tid >> 6;         // 0..7
  const int wr = wid >> 2;          // M-half of tile (128 rows)
  const int wc = wid & 3;           // N-quarter (64 cols)
  const int quad = lane >> 4;
  const int l15 = lane & 15;

  // staging: thread covers row (c*64 + tid>>3), swizzled 16B slot (tid&7)^(row&7)
  const int sr = tid >> 3;                        // 0..63
  const int ks8 = ((tid & 7) ^ (sr & 7)) << 3;    // element offset in 64-wide row
  const bf16* Ag = A + (size_t)(m0 + sr) * lda + ks8;
  const bf16* Bg = Bm + (size_t)(n0 + sr) * ldb + ks8;

  // read-side swizzle: slot (kk*4+quad) ^ (row&7); row&7 == l15&7 for all frags
  const int swz0 = ((quad) ^ (l15 & 7)) << 3;
  const int swz1 = ((4 + quad) ^ (l15 & 7)) << 3;

  f32x4 acc[8][4];
#pragma unroll
  for (int i = 0; i < 8; ++i)
#pragma unroll
    for (int j = 0; j < 4; ++j)
#pragma unroll
      for (int r = 0; r < 4; ++r) acc[i][j][r] = 0.f;

  const int NT = K >> 6;

  // stage half-tile H (rows H*128..H*128+127) of K-tile TK: 2 x stage16
#define STA_H(P, H, TK)                                                       \
  do {                                                                        \
    _Pragma("unroll") for (int j_ = 0; j_ < 2; ++j_) {                        \
      const int c_ = (H) * 2 + j_;                                            \
      stage16(Ag + (size_t)(c_ * 64) * lda + (size_t)(TK) * 64,               \
              &sA[P][c_ * 64 + wid * 8][0]);                                  \
    }                                                                         \
  } while (0)
#define STB_H(P, H, TK)                                                       \
  do {                                                                        \
    _Pragma("unroll") for (int j_ = 0; j_ < 2; ++j_) {                        \
      const int c_ = (H) * 2 + j_;                                            \
      stage16(Bg + (size_t)(c_ * 64) * ldb + (size_t)(TK) * 64,               \
              &sB[P][c_ * 64 + wid * 8][0]);                                  \
    }                                                                         \
  } while (0)

  // ping-pong fragment registers
  bf16x8 aq0[4][2], aq1[4][2], b0[2][2], b1[2][2];

#define RDA(DST, MH, BUF)                                                     \
  do {                                                                        \
    const bf16* As_ = &sA[BUF][0][0];                                         \
    _Pragma("unroll") for (int mi_ = 0; mi_ < 4; ++mi_) {                     \
      const int arow_ = wr * 128 + (MH) * 64 + mi_ * 16 + l15;                \
      DST[mi_][0] = *(const bf16x8*)(As_ + arow_ * 64 + swz0);                \
      DST[mi_][1] = *(const bf16x8*)(As_ + arow_ * 64 + swz1);                \
    }                                                                         \
  } while (0)
#define RDB(DST, NH, BUF)                                                     \
  do {                                                                        \
    const bf16* Bs_ = &sB[BUF][0][0];                                         \
    _Pragma("unroll") for (int ni_ = 0; ni_ < 2; ++ni_) {                     \
      const int brow_ = wc * 64 + (NH) * 32 + ni_ * 16 + l15;                 \
      DST[ni_][0] = *(const bf16x8*)(Bs_ + brow_ * 64 + swz0);                \
      DST[ni_][1] = *(const bf16x8*)(Bs_ + brow_ * 64 + swz1);                \
    }                                                                         \
  } while (0)
#define MFMAQ(MH, NH, AA, BB)                                                 \
  do {                                                                        \
    __builtin_amdgcn_s_setprio(1);                                            \
    _Pragma("unroll") for (int mi_ = 0; mi_ < 4; ++mi_)                       \
        _Pragma("unroll") for (int ni_ = 0; ni_ < 2; ++ni_) {                 \
      acc[(MH)*4 + mi_][(NH)*2 + ni_] = __builtin_amdgcn_mfma_f32_16x16x32_bf16( \
          AA[mi_][0], BB[ni_][0], acc[(MH)*4 + mi_][(NH)*2 + ni_], 0, 0, 0);  \
      acc[(MH)*4 + mi_][(NH)*2 + ni_] = __builtin_amdgcn_mfma_f32_16x16x32_bf16( \
          AA[mi_][1], BB[ni_][1], acc[(MH)*4 + mi_][(NH)*2 + ni_], 0, 0, 0);  \
    }                                                                         \
    __builtin_amdgcn_s_setprio(0);                                            \
  } while (0)

  // prologue (chronological stage order keeps the vmcnt ledger uniform):
  const int t1 = (NT > 1) ? 1 : 0;
  STB_H(0, 0, 0); STA_H(0, 0, 0);     // HB0(0), HA0(0)
  STB_H(0, 1, 0); STA_H(0, 1, 0);     // HB1(0), HA1(0)
  STB_H(1, 0, t1); STA_H(1, 0, t1);   // HB0(1), HA0(1)
  WAITVM(8);                          // 12 out -> retire HB0(0), HA0(0)
  SCHB();
  BARX();
  RDA(aq0, 0, 0);                     // sub0(0)
  RDB(b0, 0, 0);                      // nh0(0)

  for (int t = 0; t < NT; ++t) {
    const int p = t & 1;
    const int tn = (t + 1 < NT) ? t + 1 : NT - 1;
    const int tnn = (t + 2 < NT) ? t + 2 : NT - 1;
    // ---- ph1: MFMA(0,0) aq0 x b0 ----
    WAITVM(4);                       // retire HB1(t), HA1(t)
    SCHB();
    RDB(b1, 1, p);                   // b1(t), 4 reads
    STB_H(p ^ 1, 1, tn);             // HB1(t+1)
    MFMAQ(0, 0, aq0, b0);
    BARX();
    // ---- ph2: MFMA(0,1) aq0 x b1 ----
    RDA(aq1, 1, p);                  // sub1(t), 8 reads
    STA_H(p ^ 1, 1, tn);             // HA1(t+1)
    MFMAQ(0, 1, aq0, b1);
    BARX();
    // ---- ph3: MFMA(1,0) aq1 x b0 ----
    STB_H(p, 0, tnn);                // HB0(t+2)
    MFMAQ(1, 0, aq1, b0);
    BARX();
    // ---- ph4: MFMA(1,1) aq1 x b1 ----
    WAITVM(6);                       // retire HA0(t+1), HB0(t+1)
    SCHB();
    if (t + 1 < NT) {
      RDA(aq0, 0, p ^ 1);            // sub0(t+1), 8 reads
      RDB(b0, 0, p ^ 1);             // nh0(t+1), 4 reads
    }
    STA_H(p, 0, tnn);                // HA0(t+2)
    MFMAQ(1, 1, aq1, b1);
    BARX();
  }
  WAITVM(0);                         // drain tail stages (hygiene)

#undef STA_H
#undef STB_H
#undef RDA
#undef RDB
#undef MFMAQ

#pragma unroll
  for (int nn = 0; nn < 4; ++nn) {
    const int n = n0 + wc * 64 + nn * 16 + l15;
    const float bv = bias[n];
#pragma unroll
    for (int mm = 0; mm < 8; ++mm) {
#pragma unroll
      for (int r = 0; r < 4; ++r) {
        const int m = m0 + wr * 128 + mm * 16 + quad * 4 + r;
        float v = acc[mm][nn][r] + bv;
        if (EPI == 1) v = gelu_tanh(v);
        C[(size_t)m * ldc + n] = (TO)v;
      }
    }
  }
}

// ---------------------------------------------------------------------------
// gate pre-activation GEMM: one gate per block (z = h*2+g), 128x128 tile,
// K = DH = 256. out[m, h*DHD + n] = sum_k xconv[m, h*DHD+k] * W[g][h][n][k]
// ---------------------------------------------------------------------------
__global__ __launch_bounds__(256) void gate_gemm(
    const bf16* __restrict__ xconv,
    const bf16* __restrict__ gxT, const bf16* __restrict__ gaT,
    bf16* __restrict__ gxr, bf16* __restrict__ gar) {
  const int h = blockIdx.z >> 1;
  const int g = blockIdx.z & 1;
  const bf16* A = xconv + h * DHD;                       // lda = DDIM
  const bf16* Bm = (g ? gaT : gxT) + (size_t)h * DHD * DHD;  // ldb = DHD
  bf16* C = (g ? gar : gxr) + h * DHD;                   // ldc = DDIM
  const int n0 = blockIdx.x * 128;
  const int m0 = blockIdx.y * 128;
  __shared__ bf16 As[128 * 32];
  __shared__ bf16 Bs[128 * 32];
  const int tid = threadIdx.x;
  const int lane = tid & 63;
  const int wid = tid >> 6;
  const int waveM = wid >> 1, waveN = wid & 1;
  const int quad = lane >> 4;
  const int l15 = lane & 15;
  const int srow = lane >> 2;
  const int scol = (lane & 3) * 8;

  f32x4 acc[4][4];
#pragma unroll
  for (int i = 0; i < 4; ++i)
#pragma unroll
    for (int j = 0; j < 4; ++j)
#pragma unroll
      for (int r = 0; r < 4; ++r) acc[i][j][r] = 0.f;

  for (int k0 = 0; k0 < DHD; k0 += 32) {
    if (k0) __syncthreads();
#pragma unroll
    for (int cc = 0; cc < 2; ++cc) {
      const int q = wid * 2 + cc;
      const int row = q * 16 + srow;
      stage16(A + (size_t)(m0 + row) * DDIM + k0 + scol, As + q * 512);
      stage16(Bm + (size_t)(n0 + row) * DHD + k0 + scol, Bs + q * 512);
    }
    __syncthreads();
    bf16x8 af[4], bfr[4];
#pragma unroll
    for (int i = 0; i < 4; ++i) {
      af[i]  = *(const bf16x8*)&As[(waveM * 64 + i * 16 + l15) * 32 + quad * 8];
      bfr[i] = *(const bf16x8*)&Bs[(waveN * 64 + i * 16 + l15) * 32 + quad * 8];
    }
#pragma unroll
    for (int i = 0; i < 4; ++i)
#pragma unroll
      for (int j = 0; j < 4; ++j)
        acc[i][j] = __builtin_amdgcn_mfma_f32_16x16x32_bf16(af[i], bfr[j], acc[i][j], 0, 0, 0);
  }

#pragma unroll
  for (int j = 0; j < 4; ++j) {
    const int n = n0 + waveN * 64 + j * 16 + l15;
#pragma unroll
    for (int i = 0; i < 4; ++i) {
#pragma unroll
      for (int r = 0; r < 4; ++r) {
        const int m = m0 + waveM * 64 + i * 16 + quad * 4 + r;
        C[(size_t)m * DDIM + n] = (bf16)acc[i][j][r];
      }
    }
  }
}

// ---------------------------------------------------------------------------
// depthwise causal conv, TW=4; bf16 data, fp32 weights
// ---------------------------------------------------------------------------
__global__ __launch_bounds__(256) void conv_kernel(
    const bf16* __restrict__ xp, const float* __restrict__ cw,
    const float* __restrict__ cb, const int* __restrict__ segp,
    bf16* __restrict__ xc) {
  int v = blockIdx.x * 256 + threadIdx.x;
  int dv = v & (DDIM / 8 - 1);
  int m = v >> 8;
  int d0 = dv * 8;
  int t = m & (TDIM - 1);
  int sp = segp[m];
  float acc[8];
#pragma unroll
  for (int j = 0; j < 8; ++j) acc[j] = cb[d0 + j];
#pragma unroll
  for (int i = 0; i < 4; ++i) {
    int shift = 3 - i;
    if (t >= shift && sp >= shift) {
      bf16x8 xv = *(const bf16x8*)&xp[(size_t)(m - shift) * DDIM + d0];
#pragma unroll
      for (int j = 0; j < 8; ++j) acc[j] = fmaf((float)xv[j], cw[i * DDIM + d0 + j], acc[j]);
    }
  }
  bf16x8 o;
#pragma unroll
  for (int j = 0; j < 8; ++j) o[j] = (bf16)acc[j];
  *(bf16x8*)&xc[(size_t)m * DDIM + d0] = o;
}

// ---------------------------------------------------------------------------
// transpose + convert gate weights: dst[h][j][i] = (bf16)src[h][i][j]
// ---------------------------------------------------------------------------
__global__ __launch_bounds__(256) void transpose_gates(
    const float* __restrict__ gxw, const float* __restrict__ gaw,
    bf16* __restrict__ gxT, bf16* __restrict__ gaT) {
  __shared__ bf16 tile[32][33];
  int zz = blockIdx.z;
  int h = zz >> 1;
  const float* src = (zz & 1) ? gaw : gxw;
  bf16* dst = (zz & 1) ? gaT : gxT;
  int j0 = blockIdx.x * 32;
  int i0 = blockIdx.y * 32;
  int r = threadIdx.x >> 5;
  int c = threadIdx.x & 31;
  for (int rr = r; rr < 32; rr += 8)
    tile[rr][c] = (bf16)src[(size_t)(h * DHD + i0 + rr) * DHD + j0 + c];
  __syncthreads();
  for (int rr = r; rr < 32; rr += 8)
    dst[(size_t)(h * DHD + j0 + rr) * DHD + i0 + c] = tile[c][rr];
}

// ---------------------------------------------------------------------------
// RG-LRU elementwise recompute, shared by scan phases
// ---------------------------------------------------------------------------
__device__ __forceinline__ void lru_elem(float pgx, float pga, float xc,
                                         float spv, bool reset,
                                         float& a, float& nr) {
  const float gx = sigmoid_f(pgx);
  const float ga = sigmoid_f(pga);
  const float la = -8.f * ga * spv;
  a = reset ? 0.f : __expf(la);
  const float mult = reset ? 1.f : sqrtf(fmaxf(1.f - __expf(2.f * la), 0.f));
  nr = xc * gx * mult;
}

// chunked scan phase 1: per (b, chunk, d) compute prod(a) and h across chunk
__global__ __launch_bounds__(256) void scan_phase1(
    const bf16* __restrict__ gxr, const bf16* __restrict__ gar,
    const bf16* __restrict__ xconv,
    const float* __restrict__ gxb, const float* __restrict__ gab,
    const float* __restrict__ apar, const int* __restrict__ segp,
    float* __restrict__ chA, float* __restrict__ chH) {
  int idx = blockIdx.x * 256 + threadIdx.x;
  int d = idx & (DDIM - 1);
  int c = (idx >> 11) & (NCHUNK - 1);
  int b = idx >> 17;
  const float gxbv = gxb[d], gabv = gab[d];
  const float spv = softplus_f(apar[d]);
  const int mrow = b * TDIM + c * LCHUNK;
  size_t base = (size_t)mrow * DDIM + d;
  float A = 1.f, hh = 0.f;
  for (int i = 0; i < LCHUNK; ++i) {
    size_t o = base + (size_t)i * DDIM;
    float a, nr;
    lru_elem((float)gxr[o] + gxbv, (float)gar[o] + gabv, (float)xconv[o],
             spv, segp[mrow + i] == 0, a, nr);
    hh = fmaf(a, hh, nr);
    A *= a;
  }
  int ci = (b * NCHUNK + c) * DDIM + d;
  chA[ci] = A;
  chH[ci] = hh;
}

__global__ __launch_bounds__(256) void scan_phase2(
    const float* __restrict__ chA, const float* __restrict__ chH,
    float* __restrict__ hst) {
  int idx = blockIdx.x * 256 + threadIdx.x;
  int d = idx & (DDIM - 1);
  int b = idx >> 11;
  float s = 0.f;
  for (int c = 0; c < NCHUNK; ++c) {
    int ci = (b * NCHUNK + c) * DDIM + d;
    hst[ci] = s;
    s = fmaf(chA[ci], s, chH[ci]);
  }
}

// phase 3: replay scan with chunk-start state; z = h*y in-place over y
__global__ __launch_bounds__(256) void scan_phase3(
    const bf16* __restrict__ gxr, const bf16* __restrict__ gar,
    const bf16* __restrict__ xconv,
    const float* __restrict__ gxb, const float* __restrict__ gab,
    const float* __restrict__ apar, const int* __restrict__ segp,
    const float* __restrict__ hst, bf16* __restrict__ yz) {
  int idx = blockIdx.x * 256 + threadIdx.x;
  int d = idx & (DDIM - 1);
  int c = (idx >> 11) & (NCHUNK - 1);
  int b = idx >> 17;
  const float gxbv = gxb[d], gabv = gab[d];
  const float spv = softplus_f(apar[d]);
  const int mrow = b * TDIM + c * LCHUNK;
  size_t base = (size_t)mrow * DDIM + d;
  float hh = hst[(b * NCHUNK + c) * DDIM + d];
  for (int i = 0; i < LCHUNK; ++i) {
    size_t o = base + (size_t)i * DDIM;
    float a, nr;
    lru_elem((float)gxr[o] + gxbv, (float)gar[o] + gabv, (float)xconv[o],
             spv, segp[mrow + i] == 0, a, nr);
    hh = fmaf(a, hh, nr);
    yz[o] = (bf16)(hh * (float)yz[o]);
  }
}

// ---------------------------------------------------------------------------
extern "C" void kernel_launch(void* const* d_in, const int* in_sizes, int n_in,
                              void* d_out, int out_size, void* d_ws, size_t ws_size,
                              hipStream_t stream) {
  const float* x    = (const float*)d_in[0];
  const int*   segp = (const int*)d_in[1];
  const float* Wy   = (const float*)d_in[2];
  const float* by   = (const float*)d_in[3];
  const float* Wx   = (const float*)d_in[4];
  const float* bx   = (const float*)d_in[5];
  const float* cw   = (const float*)d_in[6];
  const float* cb   = (const float*)d_in[7];
  const float* gxw  = (const float*)d_in[8];
  const float* gxb  = (const float*)d_in[9];
  const float* gaw  = (const float*)d_in[10];
  const float* gab  = (const float*)d_in[11];
  const float* apar = (const float*)d_in[12];
  const float* Wout = (const float*)d_in[13];
  const float* bout = (const float*)d_in[14];

  const size_t MD = (size_t)MTOT * DDIM;       // 16.78M elements
  const size_t WD = (size_t)DDIM * DDIM;       // 4.19M elements
  // d_out (fp32, 67 MB) as bf16 scratch until the final GEMM:
  bf16* xb    = (bf16*)d_out;                   // lower: xb -> xconv
  bf16* xproj = (bf16*)((char*)d_out + MD * 2); // upper: xproj -> gxr
  bf16* xconv = xb;
  bf16* gxr   = xproj;

  // ws (~92 MB): gar | W1 | WB1 | WB2 | gxT | gaT | chA | chH | hst
  char* ws = (char*)d_ws;
  bf16*  gar = (bf16*)ws;                        // 33.5 MB
  bf16*  W1  = (bf16*)(ws + MD * 2);             // y -> z (33.5 MB)
  bf16*  WB1 = (bf16*)(ws + 2 * MD * 2);         // Wxb, later Woutb (8.4 MB)
  bf16*  WB2 = (bf16*)(ws + 2 * MD * 2 + WD * 2);// Wyb (8.4 MB)
  char*  tail = ws + 2 * MD * 2 + 2 * WD * 2;
  const size_t GW = (size_t)HDIM * DHD * DHD * 2;      // 1 MiB
  const size_t CH = (size_t)BDIM * NCHUNK * DDIM * 4;  // 2 MiB
  bf16*  gxT = (bf16*)tail;
  bf16*  gaT = (bf16*)(tail + GW);
  float* chA = (float*)(tail + 2 * GW);
  float* chH = (float*)(tail + 2 * GW + CH);
  float* hst = (float*)(tail + 2 * GW + 2 * CH);

  dim3 blk(256);
  f2b<<<dim3(MD / 2048), blk, 0, stream>>>(x, xb);
  f2b<<<dim3(WD / 2048), blk, 0, stream>>>(Wx, WB1);
  f2b<<<dim3(WD / 2048), blk, 0, stream>>>(Wy, WB2);
  transpose_gates<<<dim3(8, 8, 16), blk, 0, stream>>>(gxw, gaw, gxT, gaT);

  // xproj = x @ Wx^T + bx ; y = gelu(x @ Wy^T + by)   (256^2, read-ahead pipe)
  gemm256<bf16, 0><<<dim3(8, 32), dim3(512), 0, stream>>>(xb, WB1, bx, xproj, DDIM, DDIM, DDIM, DDIM);
  gemm256<bf16, 1><<<dim3(8, 32), dim3(512), 0, stream>>>(xb, WB2, by, W1, DDIM, DDIM, DDIM, DDIM);

  // xconv in-place over xb (reads xproj; xb dead after the two GEMMs)
  conv_kernel<<<dim3(MTOT * (DDIM / 8) / 256), blk, 0, stream>>>(xproj, cw, cb, segp, xconv);

  // gate pre-activations: gxr over xproj (dead), gar in ws
  gate_gemm<<<dim3(2, 64, 16), blk, 0, stream>>>(xconv, gxT, gaT, gxr, gar);

  // chunked scan with fused RG-LRU elementwise; phase3 writes z = h*y over y
  scan_phase1<<<dim3(BDIM * NCHUNK * DDIM / 256), blk, 0, stream>>>(
      gxr, gar, xconv, gxb, gab, apar, segp, chA, chH);
  scan_phase2<<<dim3(BDIM * DDIM / 256), blk, 0, stream>>>(chA, chH, hst);
  scan_phase3<<<dim3(BDIM * NCHUNK * DDIM / 256), blk, 0, stream>>>(
      gxr, gar, xconv, gxb, gab, apar, segp, hst, W1);

  // out = z @ Wout^T + bout (fp32 over all of d_out; scratch dead)
  f2b<<<dim3(WD / 2048), blk, 0, stream>>>(Wout, WB1);
  gemm256<float, 0><<<dim3(8, 32), dim3(512), 0, stream>>>(W1, WB1, bout, (float*)d_out, DDIM, DDIM, DDIM, DDIM);
}